// Round 1
// baseline (413.772 us; speedup 1.0000x reference)
//
#include <hip/hip_runtime.h>
#include <math.h>

// Chamfer k-NN (k=16, L2) on MI355X.
// Layout: grid = (N/32, B, 2dirs), block = 64 (1 wave).
// Lane l handles query (blockIdx.x*32 + (l&31)); half = l>>5 selects which
// half of the 8192 refs this lane scans. Pair (l, l^32) merges at the end.

#define TILE 256              // refs per half-tile staged in LDS
#define NF4  (TILE * 3 / 4)   // 192 float4 per half tile

__global__ __launch_bounds__(64)
void chamfer_knn_kernel(const float* __restrict__ src,
                        const float* __restrict__ tgt,
                        const float* __restrict__ flow,
                        float* __restrict__ out,
                        int N, int M, float scale)
{
    const int b    = blockIdx.y;
    const int dir  = blockIdx.z;
    const int lane = threadIdx.x;
    const int half = lane >> 5;
    const int qi   = blockIdx.x * 32 + (lane & 31);

    const int nq   = (dir == 0) ? N : M;
    const int nref = (dir == 0) ? M : N;

    // ---- load query point ----
    float qx, qy, qz;
    {
        size_t off = ((size_t)b * nq + qi) * 3;
        if (dir == 0) {                       // query = source + flow
            qx = src[off + 0] + flow[off + 0];
            qy = src[off + 1] + flow[off + 1];
            qz = src[off + 2] + flow[off + 2];
        } else {                              // query = target
            qx = tgt[off + 0];
            qy = tgt[off + 1];
            qz = tgt[off + 2];
        }
    }

    const float* refp = (dir == 0) ? tgt : src;   // dir==1 refs need +flow

    __shared__ float4 tile4[2][NF4];

    // sorted ascending top-16 squared distances, s[15] = current worst
    float s[16];
#pragma unroll
    for (int i = 0; i < 16; ++i) s[i] = 3.0e38f;

    const int half_n = nref >> 1;          // 4096
    const int nsteps = half_n / TILE;      // 16

    for (int t = 0; t < nsteps; ++t) {
        // ---- stage both half-tiles into LDS (coalesced float4) ----
#pragma unroll
        for (int ii = 0; ii < 2 * NF4 / 64; ++ii) {
            int i  = ii * 64 + lane;          // 0..383
            int h  = (i >= NF4) ? 1 : 0;
            int k2 = i - h * NF4;
            size_t e0 = ((size_t)b * nref + t * TILE + h * half_n) * 3;
            const float4* g = (const float4*)(refp + e0);
            float4 v = g[k2];
            if (dir == 1) {
                const float4* gf = (const float4*)(flow + e0);
                float4 f = gf[k2];
                v.x += f.x; v.y += f.y; v.z += f.z; v.w += f.w;
            }
            tile4[h][k2] = v;
        }
        __syncthreads();

        const float4* tp = tile4[half];
        for (int j4 = 0; j4 < TILE / 4; ++j4) {
            float4 A  = tp[j4 * 3 + 0];
            float4 Bv = tp[j4 * 3 + 1];
            float4 C  = tp[j4 * 3 + 2];

#define PROC(px, py, pz) {                                              \
            float dx = qx - (px), dy = qy - (py), dz = qz - (pz);       \
            float d2 = fmaf(dz, dz, fmaf(dy, dy, dx * dx));             \
            if (d2 < s[15]) {                                           \
                float v = d2;                                           \
                _Pragma("unroll")                                       \
                for (int ii2 = 0; ii2 < 16; ++ii2) {                    \
                    float lo = fminf(s[ii2], v);                        \
                    float hi = fmaxf(s[ii2], v);                        \
                    s[ii2] = lo; v = hi;                                \
                }                                                       \
            } }

            PROC(A.x,  A.y,  A.z)
            PROC(A.w,  Bv.x, Bv.y)
            PROC(Bv.z, Bv.w, C.x)
            PROC(C.y,  C.z,  C.w)
#undef PROC
        }
        __syncthreads();
    }

    // ---- merge lane pair (l, l^32): 16 smallest of union = min(L[i], R[15-i])
    // (bitonic-halver identity for two ascending sorted 16-lists)
    float acc = 0.0f;
#pragma unroll
    for (int i = 0; i < 16; ++i) {
        float r = __shfl_xor(s[15 - i], 32);
        float m = fminf(s[i], r);
        acc += sqrtf(m);
    }
    acc *= (1.0f / 16.0f);   // mean over k

    // ---- wave reduction (each query counted twice -> 0.5 factor in scale)
#pragma unroll
    for (int off = 32; off > 0; off >>= 1)
        acc += __shfl_down(acc, off);

    if (lane == 0) atomicAdd(out, acc * scale);
}

extern "C" void kernel_launch(void* const* d_in, const int* in_sizes, int n_in,
                              void* d_out, int out_size, void* d_ws, size_t ws_size,
                              hipStream_t stream) {
    const float* src  = (const float*)d_in[0];   // pc_source [B,N,3]
    const float* tgt  = (const float*)d_in[1];   // pc_target [B,M,3]
    const float* flow = (const float*)d_in[2];   // pred_flow [B,N,3]
    float* out = (float*)d_out;

    const int B = 2;
    const int N = in_sizes[0] / (B * 3);
    const int M = in_sizes[1] / (B * 3);

    // harness poisons d_out with 0xAA before every launch
    hipMemsetAsync(out, 0, out_size * sizeof(float), stream);

    // each query's mean-k distance is accumulated twice (lane pair), so 0.5x
    const float scale = 0.5f / (float)(B * N);

    dim3 grid(N / 32, B, 2);
    chamfer_knn_kernel<<<grid, 64, 0, stream>>>(src, tgt, flow, out, N, M, scale);
}

// Round 2
// 259.980 us; speedup vs baseline: 1.5916x; 1.5916x over previous
//
#include <hip/hip_runtime.h>
#include <math.h>

// Chamfer k-NN (k=16, L2), deferred-queue design.
// kernel0: pred = src + flow
// kernel1: per (query-chunk=256, slice of refs, b, dir) block. Each thread owns
//          one query; all threads scan the SAME 1024-ref slice (wave-uniform
//          ref loads -> s_load). Candidates passing stale tau are appended to a
//          per-lane LDS queue (no sort chain in hot loop); queues drained
//          (chain-inserted into per-lane sorted top-16) when any lane has >=8.
// kernel2: merge 8 sorted per-slice top-16 lists per query, sqrt, mean, atomic.

#define INFV    3.0e38f
#define QSTRIDE 17      // queue stride in floats (16 slots + 1 pad -> no bank conflicts)
#define NSLICE  8

__device__ __forceinline__ void chain_insert(float (&s)[16], float v) {
#pragma unroll
    for (int z = 0; z < 16; ++z) {
        float lo = fminf(s[z], v);
        v        = fmaxf(s[z], v);
        s[z] = lo;
    }
}

__global__ __launch_bounds__(256) void preadd_kernel(
    const float4* __restrict__ a, const float4* __restrict__ b,
    float4* __restrict__ o, int n4)
{
    int i = blockIdx.x * 256 + threadIdx.x;
    if (i < n4) {
        float4 x = a[i], y = b[i];
        x.x += y.x; x.y += y.y; x.z += y.z; x.w += y.w;
        o[i] = x;
    }
}

__global__ __launch_bounds__(256, 4) void knn_slice_kernel(
    const float* __restrict__ pred,   // [B][N][3] = src+flow
    const float* __restrict__ tgt,    // [B][M][3]
    float* __restrict__ topk,         // [totalInst][NSLICE][16]
    int N, int M)
{
    __shared__ float qbuf[256 * QSTRIDE];

    const int tid   = threadIdx.x;
    const int slice = blockIdx.y;
    const int z     = blockIdx.z;          // b*2 + dir
    const int b     = z >> 1, dir = z & 1;

    const int nq   = dir ? M : N;
    const int nref = dir ? N : M;
    const int qi   = blockIdx.x * 256 + tid;
    // instance base offsets: z=0 -> 0, z=1 -> N, z=2 -> N+M, z=3 -> 2N+M
    const long instBase = (long)((z >= 1 ? N : 0) + (z >= 2 ? M : 0) + (z >= 3 ? N : 0));

    const float* qp = (dir ? tgt : pred) + (size_t)b * nq * 3;
    const float* rp = (dir ? pred : tgt) + (size_t)b * nref * 3;

    const bool valid = qi < nq;
    float qx, qy, qz;
    if (valid) {
        qx = qp[(size_t)qi * 3 + 0];
        qy = qp[(size_t)qi * 3 + 1];
        qz = qp[(size_t)qi * 3 + 2];
    } else {
        // d2 overflows to +inf -> never passes tau
        qx = qy = qz = 2.0e19f;
    }

    const int slen = nref / NSLICE;
    const int base = slice * slen;
    const int jend = (slice == NSLICE - 1) ? (nref - base) : slen;
    const float* rs = rp + (size_t)base * 3;

    float s[16];
#pragma unroll
    for (int i = 0; i < 16; ++i) s[i] = INFV;
    float tau = INFV;
    int   cnt = 0;
    const int qb = tid * QSTRIDE;

    int j = 0;
    for (; j + 8 <= jend; j += 8) {
#pragma unroll
        for (int u = 0; u < 8; ++u) {
            const float* r = rs + (size_t)(j + u) * 3;   // wave-uniform -> s_load
            float dx = qx - r[0], dy = qy - r[1], dz = qz - r[2];
            float d2 = fmaf(dx, dx, fmaf(dy, dy, dz * dz));
            qbuf[qb + cnt] = d2;                 // unconditional write (slot reused on fail)
            cnt += (d2 < tau) ? 1 : 0;
        }
        if (__ballot(cnt >= 8)) {                // wave-uniform drain
            for (int i = 0;; ++i) {
                if (!__ballot(i < cnt)) break;
                float v = (i < cnt) ? qbuf[qb + i] : INFV;
                chain_insert(s, v);
            }
            cnt = 0;
            tau = s[15];
        }
    }
    for (; j < jend; ++j) {                      // tail (<8): cnt stays < 17
        const float* r = rs + (size_t)j * 3;
        float dx = qx - r[0], dy = qy - r[1], dz = qz - r[2];
        float d2 = fmaf(dx, dx, fmaf(dy, dy, dz * dz));
        qbuf[qb + cnt] = d2;
        cnt += (d2 < tau) ? 1 : 0;
    }
    // final drain
    for (int i = 0;; ++i) {
        if (!__ballot(i < cnt)) break;
        float v = (i < cnt) ? qbuf[qb + i] : INFV;
        chain_insert(s, v);
    }

    if (valid) {
        float* o = topk + ((size_t)(instBase + qi) * NSLICE + slice) * 16;
#pragma unroll
        for (int i = 0; i < 16; ++i) o[i] = s[i];
    }
}

__global__ __launch_bounds__(256) void merge_topk_kernel(
    const float* __restrict__ topk, float* __restrict__ out,
    int totalInst, float scale)
{
    const int inst = blockIdx.x * 256 + threadIdx.x;
    float acc = 0.0f;
    if (inst < totalInst) {
        float s[16];
#pragma unroll
        for (int i = 0; i < 16; ++i) s[i] = INFV;
        const float* p = topk + (size_t)inst * (NSLICE * 16);
        for (int sl = 0; sl < NSLICE; ++sl) {
            const float* q = p + sl * 16;
            for (int i = 0; i < 16; ++i) {       // slice list sorted ascending
                float v = q[i];
                if (!(v < s[15])) break;         // rest can't enter top-16
                chain_insert(s, v);
            }
        }
        float sum = 0.0f;
#pragma unroll
        for (int i = 0; i < 16; ++i) sum += sqrtf(s[i]);
        acc = sum * (1.0f / 16.0f);
    }
    // wave then block reduction
#pragma unroll
    for (int off = 32; off > 0; off >>= 1) acc += __shfl_down(acc, off);
    __shared__ float wsum[4];
    const int lane = threadIdx.x & 63, wid = threadIdx.x >> 6;
    if (lane == 0) wsum[wid] = acc;
    __syncthreads();
    if (threadIdx.x == 0)
        atomicAdd(out, (wsum[0] + wsum[1] + wsum[2] + wsum[3]) * scale);
}

extern "C" void kernel_launch(void* const* d_in, const int* in_sizes, int n_in,
                              void* d_out, int out_size, void* d_ws, size_t ws_size,
                              hipStream_t stream) {
    const float* src  = (const float*)d_in[0];   // pc_source [B,N,3]
    const float* tgt  = (const float*)d_in[1];   // pc_target [B,M,3]
    const float* flow = (const float*)d_in[2];   // pred_flow [B,N,3]
    float* out = (float*)d_out;

    const int B = 2;                              // per reference setup
    const int N = in_sizes[0] / (B * 3);
    const int M = in_sizes[1] / (B * 3);

    float* pred = (float*)d_ws;                                    // B*N*3 floats
    size_t predBytes = ((size_t)in_sizes[0] * 4 + 255) & ~(size_t)255;
    float* topk = (float*)((char*)d_ws + predBytes);               // 2*(N+M)*128 floats

    hipMemsetAsync(out, 0, out_size * sizeof(float), stream);

    int n4 = in_sizes[0] / 4;
    preadd_kernel<<<(n4 + 255) / 256, 256, 0, stream>>>(
        (const float4*)src, (const float4*)flow, (float4*)pred, n4);

    int maxq = (N > M) ? N : M;
    dim3 grid1((maxq + 255) / 256, NSLICE, 2 * B);
    knn_slice_kernel<<<grid1, 256, 0, stream>>>(pred, tgt, topk, N, M);

    int totalInst = 2 * (N + M);
    float scale = 1.0f / ((float)B * (float)N);
    merge_topk_kernel<<<(totalInst + 255) / 256, 256, 0, stream>>>(
        topk, out, totalInst, scale);
}

// Round 3
// 242.589 us; speedup vs baseline: 1.7057x; 1.0717x over previous
//
#include <hip/hip_runtime.h>
#include <math.h>

// Chamfer k-NN (k=16, L2), R3: LDS-staged refs + conflict-free deferred queue.
// kernel0: pred = src + flow
// kernel1: grid (q-chunk=256, NSLICE=8 slices, B*2 instances). Whole 1024-ref
//          slice staged in LDS (12KB); hot loop is LDS-broadcast reads + 6 VALU
//          dist + exec-masked enqueue into qbuf[cnt*256+tid] (bank = tid%32,
//          conflict-free for divergent cnt). Drain (sorted-16 chain insert)
//          only when some lane has >=8 queued.
// kernel2: merge 8 sorted per-slice top-16 lists per query, sqrt, mean, atomic.

#define INFV    3.0e38f
#define NSLICE  8
#define MAXSLEN 1024

__device__ __forceinline__ void chain_insert(float (&s)[16], float v) {
#pragma unroll
    for (int z = 0; z < 16; ++z) {
        float lo = fminf(s[z], v);
        v        = fmaxf(s[z], v);
        s[z] = lo;
    }
}

__global__ __launch_bounds__(256) void preadd_kernel(
    const float4* __restrict__ a, const float4* __restrict__ b,
    float4* __restrict__ o, int n4)
{
    int i = blockIdx.x * 256 + threadIdx.x;
    if (i < n4) {
        float4 x = a[i], y = b[i];
        x.x += y.x; x.y += y.y; x.z += y.z; x.w += y.w;
        o[i] = x;
    }
}

__global__ __launch_bounds__(256, 4) void knn_slice_kernel(
    const float* __restrict__ pred,   // [B][N][3] = src+flow
    const float* __restrict__ tgt,    // [B][M][3]
    float* __restrict__ topk,         // [totalInst][NSLICE][16]
    int N, int M)
{
    __shared__ float tile[MAXSLEN * 3];   // 12 KB: the ref slice
    __shared__ float qbuf[16 * 256];      // 16 KB: per-thread queues, stride 256

    const int tid   = threadIdx.x;
    const int slice = blockIdx.y;
    const int z     = blockIdx.z;          // b*2 + dir
    const int b     = z >> 1, dir = z & 1;

    const int nq   = dir ? M : N;
    const int nref = dir ? N : M;
    const int qi   = blockIdx.x * 256 + tid;
    const long instBase = (long)((z >= 1 ? N : 0) + (z >= 2 ? M : 0) + (z >= 3 ? N : 0));

    const float* qp = (dir ? tgt : pred) + (size_t)b * nq * 3;
    const float* rp = (dir ? pred : tgt) + (size_t)b * nref * 3;

    const int slen = nref / NSLICE;        // 1024 for 8192 refs
    const float* rs = rp + (size_t)slice * slen * 3;

    // ---- stage slice into LDS, coalesced float4 ----
    {
        const int nf4 = slen * 3 / 4;      // 768
        const float4* g4 = (const float4*)rs;
        float4* t4 = (float4*)tile;
        for (int i = tid; i < nf4; i += 256) t4[i] = g4[i];
    }

    const bool valid = qi < nq;
    float qx, qy, qz;
    if (valid) {
        qx = qp[(size_t)qi * 3 + 0];
        qy = qp[(size_t)qi * 3 + 1];
        qz = qp[(size_t)qi * 3 + 2];
    } else {
        qx = qy = qz = 2.0e19f;            // d2 -> inf, never enqueued
    }

    __syncthreads();

    float s[16];
#pragma unroll
    for (int i = 0; i < 16; ++i) s[i] = INFV;
    float tau = INFV;
    int   cnt = 0;

#define DRAIN() {                                                   \
        for (int i = 0;; ++i) {                                     \
            if (!__ballot(i < cnt)) break;                          \
            float v = (i < cnt) ? qbuf[i * 256 + tid] : INFV;       \
            chain_insert(s, v);                                     \
        }                                                           \
        cnt = 0;                                                    \
        tau = s[15];                                                \
    }

#define PROC(px, py, pz) {                                          \
        float dx = qx - (px), dy = qy - (py), dz = qz - (pz);       \
        float d2 = fmaf(dx, dx, fmaf(dy, dy, dz * dz));             \
        if (d2 < tau) { qbuf[cnt * 256 + tid] = d2; cnt++; }        \
    }

    const float4* t4 = (const float4*)tile;
    const int ngrp = slen / 8;             // 8 refs (24 floats, 6 float4) per group
    for (int g = 0; g < ngrp; ++g) {
        float4 w0 = t4[g * 6 + 0];
        float4 w1 = t4[g * 6 + 1];
        float4 w2 = t4[g * 6 + 2];
        float4 w3 = t4[g * 6 + 3];
        float4 w4 = t4[g * 6 + 4];
        float4 w5 = t4[g * 6 + 5];

        PROC(w0.x, w0.y, w0.z)
        PROC(w0.w, w1.x, w1.y)
        PROC(w1.z, w1.w, w2.x)
        PROC(w2.y, w2.z, w2.w)
        PROC(w3.x, w3.y, w3.z)
        PROC(w3.w, w4.x, w4.y)
        PROC(w4.z, w4.w, w5.x)
        PROC(w5.y, w5.z, w5.w)

        if (__ballot(cnt >= 8)) DRAIN();   // queue capacity 16: max cnt 7+8=15
    }
    DRAIN();                               // final

#undef PROC
#undef DRAIN

    if (valid) {
        float* o = topk + ((size_t)(instBase + qi) * NSLICE + slice) * 16;
#pragma unroll
        for (int i = 0; i < 16; ++i) o[i] = s[i];
    }
}

__global__ __launch_bounds__(256) void merge_topk_kernel(
    const float* __restrict__ topk, float* __restrict__ out,
    int totalInst, float scale)
{
    const int inst = blockIdx.x * 256 + threadIdx.x;
    float acc = 0.0f;
    if (inst < totalInst) {
        float s[16];
#pragma unroll
        for (int i = 0; i < 16; ++i) s[i] = INFV;
        const float* p = topk + (size_t)inst * (NSLICE * 16);
        for (int sl = 0; sl < NSLICE; ++sl) {
            const float* q = p + sl * 16;
            for (int i = 0; i < 16; ++i) {       // slice list sorted ascending
                float v = q[i];
                if (!(v < s[15])) break;         // rest can't enter top-16
                chain_insert(s, v);
            }
        }
        float sum = 0.0f;
#pragma unroll
        for (int i = 0; i < 16; ++i) sum += sqrtf(s[i]);
        acc = sum * (1.0f / 16.0f);
    }
#pragma unroll
    for (int off = 32; off > 0; off >>= 1) acc += __shfl_down(acc, off);
    __shared__ float wsum[4];
    const int lane = threadIdx.x & 63, wid = threadIdx.x >> 6;
    if (lane == 0) wsum[wid] = acc;
    __syncthreads();
    if (threadIdx.x == 0)
        atomicAdd(out, (wsum[0] + wsum[1] + wsum[2] + wsum[3]) * scale);
}

extern "C" void kernel_launch(void* const* d_in, const int* in_sizes, int n_in,
                              void* d_out, int out_size, void* d_ws, size_t ws_size,
                              hipStream_t stream) {
    const float* src  = (const float*)d_in[0];   // pc_source [B,N,3]
    const float* tgt  = (const float*)d_in[1];   // pc_target [B,M,3]
    const float* flow = (const float*)d_in[2];   // pred_flow [B,N,3]
    float* out = (float*)d_out;

    const int B = 2;                              // per reference setup
    const int N = in_sizes[0] / (B * 3);
    const int M = in_sizes[1] / (B * 3);

    float* pred = (float*)d_ws;                                    // B*N*3 floats
    size_t predBytes = ((size_t)in_sizes[0] * 4 + 255) & ~(size_t)255;
    float* topk = (float*)((char*)d_ws + predBytes);               // 2*(N+M)*NSLICE*16 floats

    hipMemsetAsync(out, 0, out_size * sizeof(float), stream);

    int n4 = in_sizes[0] / 4;
    preadd_kernel<<<(n4 + 255) / 256, 256, 0, stream>>>(
        (const float4*)src, (const float4*)flow, (float4*)pred, n4);

    int maxq = (N > M) ? N : M;
    dim3 grid1((maxq + 255) / 256, NSLICE, 2 * B);
    knn_slice_kernel<<<grid1, 256, 0, stream>>>(pred, tgt, topk, N, M);

    int totalInst = 2 * (N + M);
    float scale = 1.0f / ((float)B * (float)N);
    merge_topk_kernel<<<(totalInst + 255) / 256, 256, 0, stream>>>(
        topk, out, totalInst, scale);
}